// Round 1
// baseline (2778.998 us; speedup 1.0000x reference)
//
#include <hip/hip_runtime.h>

// Problem constants (from reference file)
#define N1_DST 50000
#define N2_DST 12000
#define N3_DST 3000
#define DH 256   // D_IN == D_H == 256
#define DOUT 64

// ---------------------------------------------------------------------------
// Scatter: agg[dst] += h[src] (256 feats), deg[dst] += 1.  4 edges per block,
// 64 lanes per edge, float4 gather + 4 scalar atomics per lane.
// ---------------------------------------------------------------------------
__global__ void scatter_kernel(const float* __restrict__ h,
                               const int* __restrict__ src,
                               const int* __restrict__ dst,
                               float* __restrict__ agg,
                               float* __restrict__ deg,
                               int E) {
    int tid  = threadIdx.x;
    int lane = tid & 63;
    int sub  = tid >> 6;
    int e = blockIdx.x * 4 + sub;
    if (e >= E) return;
    int s = src[e];
    int d = dst[e];
    const float4* hv = (const float4*)(h + (size_t)s * DH);
    float4 v = hv[lane];
    float* out = agg + (size_t)d * DH + lane * 4;
    atomicAdd(out + 0, v.x);
    atomicAdd(out + 1, v.y);
    atomicAdd(out + 2, v.z);
    atomicAdd(out + 3, v.w);
    if (lane == 0) atomicAdd(deg + d, 1.0f);
}

// ---------------------------------------------------------------------------
// Normalize: agg[i,k] /= max(deg[i], 1)
// ---------------------------------------------------------------------------
__global__ void normalize_kernel(float* __restrict__ agg,
                                 const float* __restrict__ deg,
                                 long total) {
    long i = (long)blockIdx.x * blockDim.x + threadIdx.x;
    if (i >= total) return;
    float d = deg[i >> 8];  // i / 256 (DH == 256)
    agg[i] = agg[i] / fmaxf(d, 1.0f);
}

// ---------------------------------------------------------------------------
// Fused dual GEMM: C[M,N] = Ad[:M]@Ws + An[:M]@Wn + bias  (K=256 fixed)
// 64x64 output tile per block (256 threads), BK=16, 4x4 micro-tile/thread.
// ---------------------------------------------------------------------------
template <bool RELU>
__global__ void gemm_fused(const float* __restrict__ Ad,
                           const float* __restrict__ An,
                           const float* __restrict__ Ws,
                           const float* __restrict__ Wn,
                           const float* __restrict__ bias,
                           float* __restrict__ C,
                           int M, int N) {
    const int K = 256;
    __shared__ float As[16][65];  // [k][m], padded
    __shared__ float Bs[16][64];  // [k][n]

    int tid = threadIdx.x;
    int tx = tid & 15;   // output col group
    int ty = tid >> 4;   // output row group
    int row0 = blockIdx.y * 64;
    int col0 = blockIdx.x * 64;

    float acc[4][4] = {};

    for (int pass = 0; pass < 2; ++pass) {
        const float* A = pass ? An : Ad;
        const float* W = pass ? Wn : Ws;
        for (int k0 = 0; k0 < K; k0 += 16) {
            // Load A tile (64 rows x 16 k), one float4 per thread, store transposed
            {
                int r  = tid >> 2;  // 0..63
                int cq = tid & 3;   // 0..3 (k quad)
                int row = row0 + r;
                float4 v = make_float4(0.f, 0.f, 0.f, 0.f);
                if (row < M) v = *(const float4*)(A + (size_t)row * K + k0 + cq * 4);
                As[cq * 4 + 0][r] = v.x;
                As[cq * 4 + 1][r] = v.y;
                As[cq * 4 + 2][r] = v.z;
                As[cq * 4 + 3][r] = v.w;
            }
            // Load B tile (16 k x 64 cols), one float4 per thread
            {
                int r  = tid >> 4;  // 0..15
                int c4 = tid & 15;  // 0..15
                float4 v = *(const float4*)(W + (size_t)(k0 + r) * N + col0 + c4 * 4);
                *(float4*)(&Bs[r][c4 * 4]) = v;
            }
            __syncthreads();
#pragma unroll
            for (int kk = 0; kk < 16; ++kk) {
                float a[4], b[4];
#pragma unroll
                for (int i = 0; i < 4; ++i) a[i] = As[kk][ty * 4 + i];
#pragma unroll
                for (int j = 0; j < 4; ++j) b[j] = Bs[kk][tx * 4 + j];
#pragma unroll
                for (int i = 0; i < 4; ++i)
#pragma unroll
                    for (int j = 0; j < 4; ++j) acc[i][j] += a[i] * b[j];
            }
            __syncthreads();
        }
    }

#pragma unroll
    for (int i = 0; i < 4; ++i) {
        int row = row0 + ty * 4 + i;
        if (row >= M) continue;
#pragma unroll
        for (int j = 0; j < 4; ++j) {
            int col = col0 + tx * 4 + j;
            float v = acc[i][j] + bias[col];
            if (RELU) v = fmaxf(v, 0.0f);
            C[(size_t)row * N + col] = v;
        }
    }
}

extern "C" void kernel_launch(void* const* d_in, const int* in_sizes, int n_in,
                              void* d_out, int out_size, void* d_ws, size_t ws_size,
                              hipStream_t stream) {
    const float* x    = (const float*)d_in[0];
    const int* src0   = (const int*)d_in[1];
    const int* dst0   = (const int*)d_in[2];
    const int* src1   = (const int*)d_in[3];
    const int* dst1   = (const int*)d_in[4];
    const int* src2   = (const int*)d_in[5];
    const int* dst2   = (const int*)d_in[6];
    // d_in[7..9] = num_dst scalars (hardcoded as N1_DST/N2_DST/N3_DST)
    const float* Ws0  = (const float*)d_in[10];
    const float* Wn0  = (const float*)d_in[11];
    const float* b0   = (const float*)d_in[12];
    const float* Ws1  = (const float*)d_in[13];
    const float* Wn1  = (const float*)d_in[14];
    const float* b1   = (const float*)d_in[15];
    const float* Ws2  = (const float*)d_in[16];
    const float* Wn2  = (const float*)d_in[17];
    const float* b2   = (const float*)d_in[18];
    float* out = (float*)d_out;

    int E0 = in_sizes[1];
    int E1 = in_sizes[3];
    int E2 = in_sizes[5];

    // Workspace layout (floats). All offsets are multiples of 4 -> 16B aligned.
    float* ws   = (float*)d_ws;
    float* agg0 = ws;                               // N1*256
    float* deg0 = agg0 + (size_t)N1_DST * DH;       // N1
    float* agg1 = deg0 + N1_DST;                    // N2*256
    float* deg1 = agg1 + (size_t)N2_DST * DH;       // N2
    float* agg2 = deg1 + N2_DST;                    // N3*256
    float* deg2 = agg2 + (size_t)N3_DST * DH;       // N3
    float* h1   = deg2 + N3_DST;                    // N1*256
    float* h2   = h1 + (size_t)N1_DST * DH;         // N2*256

    // Zero all agg/deg buffers in one shot (ws is poisoned to 0xAA each call)
    size_t zero_count = (size_t)N1_DST * DH + N1_DST
                      + (size_t)N2_DST * DH + N2_DST
                      + (size_t)N3_DST * DH + N3_DST;
    hipMemsetAsync(ws, 0, zero_count * sizeof(float), stream);

    // ---- Layer 0: x -> h1 ----
    scatter_kernel<<<(E0 + 3) / 4, 256, 0, stream>>>(x, src0, dst0, agg0, deg0, E0);
    long t0 = (long)N1_DST * DH;
    normalize_kernel<<<(int)((t0 + 255) / 256), 256, 0, stream>>>(agg0, deg0, t0);
    dim3 g0(DH / 64, (N1_DST + 63) / 64);
    gemm_fused<false><<<g0, 256, 0, stream>>>(x, agg0, Ws0, Wn0, b0, h1, N1_DST, DH);

    // ---- Layer 1: h1 -> h2 (with ReLU) ----
    scatter_kernel<<<(E1 + 3) / 4, 256, 0, stream>>>(h1, src1, dst1, agg1, deg1, E1);
    long t1 = (long)N2_DST * DH;
    normalize_kernel<<<(int)((t1 + 255) / 256), 256, 0, stream>>>(agg1, deg1, t1);
    dim3 g1(DH / 64, (N2_DST + 63) / 64);
    gemm_fused<true><<<g1, 256, 0, stream>>>(h1, agg1, Ws1, Wn1, b1, h2, N2_DST, DH);

    // ---- Layer 2: h2 -> out ----
    scatter_kernel<<<(E2 + 3) / 4, 256, 0, stream>>>(h2, src2, dst2, agg2, deg2, E2);
    long t2 = (long)N3_DST * DH;
    normalize_kernel<<<(int)((t2 + 255) / 256), 256, 0, stream>>>(agg2, deg2, t2);
    dim3 g2(DOUT / 64, (N3_DST + 63) / 64);
    gemm_fused<false><<<g2, 256, 0, stream>>>(h2, agg2, Ws2, Wn2, b2, out, N3_DST, DOUT);
}

// Round 2
// 879.253 us; speedup vs baseline: 3.1606x; 3.1606x over previous
//
#include <hip/hip_runtime.h>

// Problem constants (from reference file)
#define N1_DST 50000
#define N2_DST 12000
#define N3_DST 3000
#define DH 256   // D_IN == D_H == 256
#define DOUT 64
#define E0_MAX 500000

// ---------------------------------------------------------------------------
// CSR build step 1: histogram of dst
// ---------------------------------------------------------------------------
__global__ void hist_kernel(const int* __restrict__ dst, int* __restrict__ cnt, int E) {
    int e = blockIdx.x * 256 + threadIdx.x;
    if (e < E) atomicAdd(&cnt[dst[e]], 1);
}

// ---------------------------------------------------------------------------
// CSR build step 2: single-block exclusive scan of cnt[0..n) -> off[0..n],
// off[n] = E total. Also initializes cursor[i] = off[i].
// ---------------------------------------------------------------------------
__global__ void scan_kernel(const int* __restrict__ cnt, int* __restrict__ off,
                            int* __restrict__ cursor, int n) {
    __shared__ int buf[1024];
    int tid = threadIdx.x;
    int chunk = (n + 1023) / 1024;
    int start = tid * chunk;
    int end = min(start + chunk, n);
    int s = 0;
    for (int i = start; i < end; ++i) s += cnt[i];
    buf[tid] = s;
    __syncthreads();
    // Hillis-Steele inclusive scan over 1024 partials
    for (int d = 1; d < 1024; d <<= 1) {
        int v = (tid >= d) ? buf[tid - d] : 0;
        __syncthreads();
        buf[tid] += v;
        __syncthreads();
    }
    int base = buf[tid] - s;  // exclusive prefix for this thread's chunk
    for (int i = start; i < end; ++i) {
        off[i] = base;
        cursor[i] = base;
        base += cnt[i];
    }
    if (tid == 1023) off[n] = buf[1023];
}

// ---------------------------------------------------------------------------
// CSR build step 3: fill edge source-index lists
// ---------------------------------------------------------------------------
__global__ void fill_kernel(const int* __restrict__ src, const int* __restrict__ dst,
                            int* __restrict__ cursor, int* __restrict__ eidx, int E) {
    int e = blockIdx.x * 256 + threadIdx.x;
    if (e < E) {
        int p = atomicAdd(&cursor[dst[e]], 1);
        eidx[p] = src[e];
    }
}

// ---------------------------------------------------------------------------
// Gather-mean: one wave per dst row. hn[d] = mean over incident src rows of h.
// Fuses the normalize step (divide by max(deg,1)).
// ---------------------------------------------------------------------------
__global__ void gather_mean_kernel(const float* __restrict__ h,
                                   const int* __restrict__ off,
                                   const int* __restrict__ eidx,
                                   float* __restrict__ hn,
                                   int num_dst) {
    int w = blockIdx.x * 4 + (threadIdx.x >> 6);
    int lane = threadIdx.x & 63;
    if (w >= num_dst) return;
    int beg = off[w];
    int end = off[w + 1];
    float4 acc = make_float4(0.f, 0.f, 0.f, 0.f);
    for (int i = beg; i < end; ++i) {
        int s = eidx[i];
        float4 v = ((const float4*)(h + (size_t)s * DH))[lane];
        acc.x += v.x; acc.y += v.y; acc.z += v.z; acc.w += v.w;
    }
    float inv = 1.0f / fmaxf((float)(end - beg), 1.0f);
    acc.x *= inv; acc.y *= inv; acc.z *= inv; acc.w *= inv;
    ((float4*)(hn + (size_t)w * DH))[lane] = acc;
}

// ---------------------------------------------------------------------------
// Fused dual GEMM: C[M,N] = Ad[:M]@Ws + An[:M]@Wn + bias  (K=256 fixed)
// 64x64 output tile per block (256 threads), BK=16, 4x4 micro-tile/thread.
// ---------------------------------------------------------------------------
template <bool RELU>
__global__ void gemm_fused(const float* __restrict__ Ad,
                           const float* __restrict__ An,
                           const float* __restrict__ Ws,
                           const float* __restrict__ Wn,
                           const float* __restrict__ bias,
                           float* __restrict__ C,
                           int M, int N) {
    const int K = 256;
    __shared__ float As[16][65];  // [k][m], padded
    __shared__ float Bs[16][64];  // [k][n]

    int tid = threadIdx.x;
    int tx = tid & 15;   // output col group
    int ty = tid >> 4;   // output row group
    int row0 = blockIdx.y * 64;
    int col0 = blockIdx.x * 64;

    float acc[4][4] = {};

    for (int pass = 0; pass < 2; ++pass) {
        const float* A = pass ? An : Ad;
        const float* W = pass ? Wn : Ws;
        for (int k0 = 0; k0 < K; k0 += 16) {
            {
                int r  = tid >> 2;  // 0..63
                int cq = tid & 3;   // 0..3 (k quad)
                int row = row0 + r;
                float4 v = make_float4(0.f, 0.f, 0.f, 0.f);
                if (row < M) v = *(const float4*)(A + (size_t)row * K + k0 + cq * 4);
                As[cq * 4 + 0][r] = v.x;
                As[cq * 4 + 1][r] = v.y;
                As[cq * 4 + 2][r] = v.z;
                As[cq * 4 + 3][r] = v.w;
            }
            {
                int r  = tid >> 4;  // 0..15
                int c4 = tid & 15;  // 0..15
                float4 v = *(const float4*)(W + (size_t)(k0 + r) * N + col0 + c4 * 4);
                *(float4*)(&Bs[r][c4 * 4]) = v;
            }
            __syncthreads();
#pragma unroll
            for (int kk = 0; kk < 16; ++kk) {
                float a[4], b[4];
#pragma unroll
                for (int i = 0; i < 4; ++i) a[i] = As[kk][ty * 4 + i];
#pragma unroll
                for (int j = 0; j < 4; ++j) b[j] = Bs[kk][tx * 4 + j];
#pragma unroll
                for (int i = 0; i < 4; ++i)
#pragma unroll
                    for (int j = 0; j < 4; ++j) acc[i][j] += a[i] * b[j];
            }
            __syncthreads();
        }
    }

#pragma unroll
    for (int i = 0; i < 4; ++i) {
        int row = row0 + ty * 4 + i;
        if (row >= M) continue;
#pragma unroll
        for (int j = 0; j < 4; ++j) {
            int col = col0 + tx * 4 + j;
            float v = acc[i][j] + bias[col];
            if (RELU) v = fmaxf(v, 0.0f);
            C[(size_t)row * N + col] = v;
        }
    }
}

// Helper: run one SAGE layer's aggregation (CSR build + gather-mean)
static void aggregate(const float* h, const int* src, const int* dst, int E, int num_dst,
                      int* cnt, int* off, int* cursor, int* eidx, float* hn,
                      hipStream_t stream) {
    hipMemsetAsync(cnt, 0, num_dst * sizeof(int), stream);
    hist_kernel<<<(E + 255) / 256, 256, 0, stream>>>(dst, cnt, E);
    scan_kernel<<<1, 1024, 0, stream>>>(cnt, off, cursor, num_dst);
    fill_kernel<<<(E + 255) / 256, 256, 0, stream>>>(src, dst, cursor, eidx, E);
    gather_mean_kernel<<<(num_dst + 3) / 4, 256, 0, stream>>>(h, off, eidx, hn, num_dst);
}

extern "C" void kernel_launch(void* const* d_in, const int* in_sizes, int n_in,
                              void* d_out, int out_size, void* d_ws, size_t ws_size,
                              hipStream_t stream) {
    const float* x    = (const float*)d_in[0];
    const int* src0   = (const int*)d_in[1];
    const int* dst0   = (const int*)d_in[2];
    const int* src1   = (const int*)d_in[3];
    const int* dst1   = (const int*)d_in[4];
    const int* src2   = (const int*)d_in[5];
    const int* dst2   = (const int*)d_in[6];
    const float* Ws0  = (const float*)d_in[10];
    const float* Wn0  = (const float*)d_in[11];
    const float* b0   = (const float*)d_in[12];
    const float* Ws1  = (const float*)d_in[13];
    const float* Wn1  = (const float*)d_in[14];
    const float* b1   = (const float*)d_in[15];
    const float* Ws2  = (const float*)d_in[16];
    const float* Wn2  = (const float*)d_in[17];
    const float* b2   = (const float*)d_in[18];
    float* out = (float*)d_out;

    int E0 = in_sizes[1];
    int E1 = in_sizes[3];
    int E2 = in_sizes[5];

    // Workspace layout (4-byte elements; all offsets 16B aligned)
    float* ws  = (float*)d_ws;
    float* hn0 = ws;                              // N1*256
    float* hn1 = hn0 + (size_t)N1_DST * DH;       // N2*256
    float* hn2 = hn1 + (size_t)N2_DST * DH;       // N3*256
    float* h1  = hn2 + (size_t)N3_DST * DH;       // N1*256
    float* h2  = h1 + (size_t)N1_DST * DH;        // N2*256
    int* cnt    = (int*)(h2 + (size_t)N2_DST * DH);  // max N1
    int* off    = cnt + N1_DST;                      // max N1+1
    int* cursor = off + N1_DST + 4;                  // max N1
    int* eidx   = cursor + N1_DST;                   // max E0

    // ---- Layer 0: x -> h1 ----
    aggregate(x, src0, dst0, E0, N1_DST, cnt, off, cursor, eidx, hn0, stream);
    dim3 g0(DH / 64, (N1_DST + 63) / 64);
    gemm_fused<false><<<g0, 256, 0, stream>>>(x, hn0, Ws0, Wn0, b0, h1, N1_DST, DH);

    // ---- Layer 1: h1 -> h2 (with ReLU) ----
    aggregate(h1, src1, dst1, E1, N2_DST, cnt, off, cursor, eidx, hn1, stream);
    dim3 g1(DH / 64, (N2_DST + 63) / 64);
    gemm_fused<true><<<g1, 256, 0, stream>>>(h1, hn1, Ws1, Wn1, b1, h2, N2_DST, DH);

    // ---- Layer 2: h2 -> out ----
    aggregate(h2, src2, dst2, E2, N3_DST, cnt, off, cursor, eidx, hn2, stream);
    dim3 g2(DOUT / 64, (N3_DST + 63) / 64);
    gemm_fused<false><<<g2, 256, 0, stream>>>(h2, hn2, Ws2, Wn2, b2, out, N3_DST, DOUT);
}

// Round 3
// 694.100 us; speedup vs baseline: 4.0037x; 1.2668x over previous
//
#include <hip/hip_runtime.h>

// Problem constants (from reference file)
#define N1_DST 50000
#define N2_DST 12000
#define N3_DST 3000
#define DH 256   // D_IN == D_H == 256
#define DOUT 64

typedef __attribute__((ext_vector_type(8))) short short8;
typedef __attribute__((ext_vector_type(4))) float f32x4;

__device__ __forceinline__ ushort f2bf(float f) {
    union { float f; uint32_t u; } v; v.f = f;
    uint32_t r = (v.u + 0x7FFF + ((v.u >> 16) & 1)) >> 16;  // RNE
    return (ushort)r;
}
__device__ __forceinline__ float bf2f(ushort u) {
    union { uint32_t u; float f; } v; v.u = ((uint32_t)u) << 16;
    return v.f;
}

// ---------------------------------------------------------------------------
// fp32 -> bf16 bulk convert (n multiple of 4)
// ---------------------------------------------------------------------------
__global__ void f32_to_bf16_kernel(const float* __restrict__ in,
                                   ushort* __restrict__ out, long n) {
    long i = ((long)blockIdx.x * 256 + threadIdx.x) * 4;
    if (i >= n) return;
    float4 v = *(const float4*)(in + i);
    ushort4 o;
    o.x = f2bf(v.x); o.y = f2bf(v.y); o.z = f2bf(v.z); o.w = f2bf(v.w);
    *(ushort4*)(out + i) = o;
}

// ---------------------------------------------------------------------------
// Weight transpose+convert: W[K][N] fp32 -> Wt[N][K] bf16.  K=256 fixed.
// ---------------------------------------------------------------------------
__global__ void transpose_w_kernel(const float* __restrict__ W,
                                   ushort* __restrict__ Wt, int Ndim) {
    int id = blockIdx.x * 256 + threadIdx.x;  // id = n*256 + k
    int n = id >> 8;
    int k = id & 255;
    if (n >= Ndim) return;
    Wt[id] = f2bf(W[k * Ndim + n]);
}

// ---------------------------------------------------------------------------
// CSR build
// ---------------------------------------------------------------------------
__global__ void hist_kernel(const int* __restrict__ dst, int* __restrict__ cnt, int E) {
    int e = blockIdx.x * 256 + threadIdx.x;
    if (e < E) atomicAdd(&cnt[dst[e]], 1);
}

__global__ void scan_kernel(const int* __restrict__ cnt, int* __restrict__ off,
                            int* __restrict__ cursor, int n) {
    __shared__ int buf[1024];
    int tid = threadIdx.x;
    int chunk = (n + 1023) / 1024;
    int start = tid * chunk;
    int end = min(start + chunk, n);
    int s = 0;
    for (int i = start; i < end; ++i) s += cnt[i];
    buf[tid] = s;
    __syncthreads();
    for (int d = 1; d < 1024; d <<= 1) {
        int v = (tid >= d) ? buf[tid - d] : 0;
        __syncthreads();
        buf[tid] += v;
        __syncthreads();
    }
    int base = buf[tid] - s;
    for (int i = start; i < end; ++i) {
        off[i] = base;
        cursor[i] = base;
        base += cnt[i];
    }
    if (tid == 1023) off[n] = buf[1023];
}

__global__ void fill_kernel(const int* __restrict__ src, const int* __restrict__ dst,
                            int* __restrict__ cursor, int* __restrict__ eidx, int E) {
    int e = blockIdx.x * 256 + threadIdx.x;
    if (e < E) {
        int p = atomicAdd(&cursor[dst[e]], 1);
        eidx[p] = src[e];
    }
}

// ---------------------------------------------------------------------------
// Gather-mean, fp32 input -> bf16 output. One wave per dst; lane owns 4 feats.
// ---------------------------------------------------------------------------
__global__ void gather_mean_f32_kernel(const float* __restrict__ h,
                                       const int* __restrict__ off,
                                       const int* __restrict__ eidx,
                                       ushort* __restrict__ hn,
                                       int num_dst) {
    int w = blockIdx.x * 4 + (threadIdx.x >> 6);
    int lane = threadIdx.x & 63;
    if (w >= num_dst) return;
    int beg = off[w];
    int end = off[w + 1];
    float4 acc = make_float4(0.f, 0.f, 0.f, 0.f);
    for (int i = beg; i < end; ++i) {
        int s = eidx[i];
        float4 v = ((const float4*)(h + (size_t)s * DH))[lane];
        acc.x += v.x; acc.y += v.y; acc.z += v.z; acc.w += v.w;
    }
    float inv = 1.0f / fmaxf((float)(end - beg), 1.0f);
    ushort4 o;
    o.x = f2bf(acc.x * inv); o.y = f2bf(acc.y * inv);
    o.z = f2bf(acc.z * inv); o.w = f2bf(acc.w * inv);
    *(ushort4*)(hn + (size_t)w * DH + lane * 4) = o;
}

// ---------------------------------------------------------------------------
// Gather-mean, bf16 input -> bf16 output. One wave per dst; lane owns 4 feats.
// ---------------------------------------------------------------------------
__global__ void gather_mean_bf16_kernel(const ushort* __restrict__ h,
                                        const int* __restrict__ off,
                                        const int* __restrict__ eidx,
                                        ushort* __restrict__ hn,
                                        int num_dst) {
    int w = blockIdx.x * 4 + (threadIdx.x >> 6);
    int lane = threadIdx.x & 63;
    if (w >= num_dst) return;
    int beg = off[w];
    int end = off[w + 1];
    float a0 = 0.f, a1 = 0.f, a2 = 0.f, a3 = 0.f;
    for (int i = beg; i < end; ++i) {
        int s = eidx[i];
        ushort4 v = ((const ushort4*)(h + (size_t)s * DH))[lane];
        a0 += bf2f(v.x); a1 += bf2f(v.y); a2 += bf2f(v.z); a3 += bf2f(v.w);
    }
    float inv = 1.0f / fmaxf((float)(end - beg), 1.0f);
    ushort4 o;
    o.x = f2bf(a0 * inv); o.y = f2bf(a1 * inv);
    o.z = f2bf(a2 * inv); o.w = f2bf(a3 * inv);
    *(ushort4*)(hn + (size_t)w * DH + lane * 4) = o;
}

// ---------------------------------------------------------------------------
// MFMA dual GEMM: C[M,N] = Ad@Ws + An@Wn + bias (K=256). A: M x K bf16
// row-major. Wt: N x K bf16 (pre-transposed). Block: 128x64 tile, 4 waves,
// each wave 32x64 via 2x4 grid of 16x16x32 MFMAs.
// ---------------------------------------------------------------------------
template <bool RELU, bool OUT_BF16>
__global__ void gemm_mfma(const ushort* __restrict__ Ad,
                          const ushort* __restrict__ An,
                          const ushort* __restrict__ Wst,
                          const ushort* __restrict__ Wnt,
                          const float* __restrict__ bias,
                          void* __restrict__ Cv,
                          int M, int N) {
    const int K = 256;
    const int LDK = 40;  // padded k-stride (shorts): 80B rows, 16B-aligned
    __shared__ ushort As[128 * LDK];
    __shared__ ushort Bs[64 * LDK];

    int tid  = threadIdx.x;
    int lane = tid & 63;
    int wid  = tid >> 6;
    int quad = lane >> 4;
    int mr   = lane & 15;
    int row0 = blockIdx.y * 128;
    int col0 = blockIdx.x * 64;

    f32x4 acc[2][4];
#pragma unroll
    for (int i = 0; i < 2; ++i)
#pragma unroll
        for (int j = 0; j < 4; ++j) acc[i][j] = (f32x4){0.f, 0.f, 0.f, 0.f};

    for (int pass = 0; pass < 2; ++pass) {
        const ushort* A  = pass ? An : Ad;
        const ushort* Wt = pass ? Wnt : Wst;
        for (int k0 = 0; k0 < K; k0 += 32) {
            // Stage A tile: 128 rows x 32 k = 512 chunks of 8 bf16; 2/thread
#pragma unroll
            for (int c = 0; c < 2; ++c) {
                int chunk = tid + c * 256;
                int r   = chunk >> 2;
                int seg = chunk & 3;
                int row = row0 + r;
                uint4 v = make_uint4(0u, 0u, 0u, 0u);
                if (row < M) v = *(const uint4*)(A + (size_t)row * K + k0 + seg * 8);
                *(uint4*)(&As[r * LDK + seg * 8]) = v;
            }
            // Stage B tile: 64 n-rows x 32 k; 1 chunk/thread
            {
                int n   = tid >> 2;
                int seg = tid & 3;
                uint4 v = *(const uint4*)(Wt + (size_t)(col0 + n) * K + k0 + seg * 8);
                *(uint4*)(&Bs[n * LDK + seg * 8]) = v;
            }
            __syncthreads();
            short8 a[2], b[4];
#pragma unroll
            for (int mt = 0; mt < 2; ++mt)
                a[mt] = *(const short8*)(&As[(wid * 32 + mt * 16 + mr) * LDK + quad * 8]);
#pragma unroll
            for (int nt = 0; nt < 4; ++nt)
                b[nt] = *(const short8*)(&Bs[(nt * 16 + mr) * LDK + quad * 8]);
#pragma unroll
            for (int mt = 0; mt < 2; ++mt)
#pragma unroll
                for (int nt = 0; nt < 4; ++nt)
                    acc[mt][nt] = __builtin_amdgcn_mfma_f32_16x16x32_bf16(
                        a[mt], b[nt], acc[mt][nt], 0, 0, 0);
            __syncthreads();
        }
    }

    // Epilogue: C/D layout col = lane&15, row = quad*4 + reg
#pragma unroll
    for (int mt = 0; mt < 2; ++mt) {
#pragma unroll
        for (int i = 0; i < 4; ++i) {
            int row = row0 + wid * 32 + mt * 16 + quad * 4 + i;
            if (row >= M) continue;
#pragma unroll
            for (int nt = 0; nt < 4; ++nt) {
                int col = col0 + nt * 16 + mr;
                float v = acc[mt][nt][i] + bias[col];
                if (RELU) v = fmaxf(v, 0.0f);
                if (OUT_BF16) ((ushort*)Cv)[(size_t)row * N + col] = f2bf(v);
                else          ((float*)Cv)[(size_t)row * N + col] = v;
            }
        }
    }
}

// Helper: one layer's aggregation (CSR build + gather-mean)
static void build_csr(const int* src, const int* dst, int E, int num_dst,
                      int* cnt, int* off, int* cursor, int* eidx,
                      hipStream_t stream) {
    hipMemsetAsync(cnt, 0, num_dst * sizeof(int), stream);
    hist_kernel<<<(E + 255) / 256, 256, 0, stream>>>(dst, cnt, E);
    scan_kernel<<<1, 1024, 0, stream>>>(cnt, off, cursor, num_dst);
    fill_kernel<<<(E + 255) / 256, 256, 0, stream>>>(src, dst, cursor, eidx, E);
}

extern "C" void kernel_launch(void* const* d_in, const int* in_sizes, int n_in,
                              void* d_out, int out_size, void* d_ws, size_t ws_size,
                              hipStream_t stream) {
    const float* x    = (const float*)d_in[0];
    const int* src0   = (const int*)d_in[1];
    const int* dst0   = (const int*)d_in[2];
    const int* src1   = (const int*)d_in[3];
    const int* dst1   = (const int*)d_in[4];
    const int* src2   = (const int*)d_in[5];
    const int* dst2   = (const int*)d_in[6];
    const float* Ws0  = (const float*)d_in[10];
    const float* Wn0  = (const float*)d_in[11];
    const float* b0   = (const float*)d_in[12];
    const float* Ws1  = (const float*)d_in[13];
    const float* Wn1  = (const float*)d_in[14];
    const float* b1   = (const float*)d_in[15];
    const float* Ws2  = (const float*)d_in[16];
    const float* Wn2  = (const float*)d_in[17];
    const float* b2   = (const float*)d_in[18];
    float* out = (float*)d_out;

    int E0 = in_sizes[1];
    int E1 = in_sizes[3];
    int E2 = in_sizes[5];

    // Workspace layout (shorts first, then ints; all 16B aligned)
    ushort* wsu  = (ushort*)d_ws;
    ushort* xb   = wsu;                               // N1*256
    ushort* hn0b = xb   + (size_t)N1_DST * DH;        // N1*256
    ushort* h1b  = hn0b + (size_t)N1_DST * DH;        // N1*256
    ushort* hn1b = h1b  + (size_t)N1_DST * DH;        // N2*256
    ushort* h2b  = hn1b + (size_t)N2_DST * DH;        // N2*256
    ushort* hn2b = h2b  + (size_t)N2_DST * DH;        // N3*256
    ushort* Ws0t = hn2b + (size_t)N3_DST * DH;        // 256*256
    ushort* Wn0t = Ws0t + 256 * 256;
    ushort* Ws1t = Wn0t + 256 * 256;
    ushort* Wn1t = Ws1t + 256 * 256;
    ushort* Ws2t = Wn1t + 256 * 256;                  // 64*256
    ushort* Wn2t = Ws2t + 64 * 256;
    int* cnt    = (int*)(Wn2t + 64 * 256);            // max N1
    int* off    = cnt + N1_DST;                       // max N1+1
    int* cursor = off + N1_DST + 4;                   // max N1
    int* eidx   = cursor + N1_DST;                    // max E0

    // --- One-time per call: convert x[:N1] and all weights to bf16 ---
    long nxb = (long)N1_DST * DH;
    f32_to_bf16_kernel<<<(int)((nxb / 4 + 255) / 256), 256, 0, stream>>>(x, xb, nxb);
    transpose_w_kernel<<<(256 * 256 + 255) / 256, 256, 0, stream>>>(Ws0, Ws0t, 256);
    transpose_w_kernel<<<(256 * 256 + 255) / 256, 256, 0, stream>>>(Wn0, Wn0t, 256);
    transpose_w_kernel<<<(256 * 256 + 255) / 256, 256, 0, stream>>>(Ws1, Ws1t, 256);
    transpose_w_kernel<<<(256 * 256 + 255) / 256, 256, 0, stream>>>(Wn1, Wn1t, 256);
    transpose_w_kernel<<<(64 * 256 + 255) / 256, 256, 0, stream>>>(Ws2, Ws2t, 64);
    transpose_w_kernel<<<(64 * 256 + 255) / 256, 256, 0, stream>>>(Wn2, Wn2t, 64);

    // ---- Layer 0: x -> h1 ----
    build_csr(src0, dst0, E0, N1_DST, cnt, off, cursor, eidx, stream);
    gather_mean_f32_kernel<<<(N1_DST + 3) / 4, 256, 0, stream>>>(x, off, eidx, hn0b, N1_DST);
    {
        dim3 g(DH / 64, (N1_DST + 127) / 128);
        gemm_mfma<false, true><<<g, 256, 0, stream>>>(xb, hn0b, Ws0t, Wn0t, b0, h1b, N1_DST, DH);
    }

    // ---- Layer 1: h1 -> h2 (ReLU on output) ----
    build_csr(src1, dst1, E1, N2_DST, cnt, off, cursor, eidx, stream);
    gather_mean_bf16_kernel<<<(N2_DST + 3) / 4, 256, 0, stream>>>(h1b, off, eidx, hn1b, N2_DST);
    {
        dim3 g(DH / 64, (N2_DST + 127) / 128);
        gemm_mfma<true, true><<<g, 256, 0, stream>>>(h1b, hn1b, Ws1t, Wn1t, b1, h2b, N2_DST, DH);
    }

    // ---- Layer 2: h2 -> out (fp32 output) ----
    build_csr(src2, dst2, E2, N3_DST, cnt, off, cursor, eidx, stream);
    gather_mean_bf16_kernel<<<(N3_DST + 3) / 4, 256, 0, stream>>>(h2b, off, eidx, hn2b, N3_DST);
    {
        dim3 g(DOUT / 64, (N3_DST + 127) / 128);
        gemm_mfma<false, false><<<g, 256, 0, stream>>>(h2b, hn2b, Ws2t, Wn2t, b2, out, N3_DST, DOUT);
    }
}

// Round 4
// 570.612 us; speedup vs baseline: 4.8702x; 1.2164x over previous
//
#include <hip/hip_runtime.h>

// Problem constants (from reference file)
#define N0_SRC 200000
#define N1_DST 50000
#define N2_DST 12000
#define N3_DST 3000
#define DH 256   // D_IN == D_H == 256
#define DOUT 64

typedef __attribute__((ext_vector_type(8))) short short8;
typedef __attribute__((ext_vector_type(4))) float f32x4;

__device__ __forceinline__ ushort f2bf(float f) {
    union { float f; uint32_t u; } v; v.f = f;
    uint32_t r = (v.u + 0x7FFF + ((v.u >> 16) & 1)) >> 16;  // RNE
    return (ushort)r;
}
__device__ __forceinline__ float bf2f(ushort u) {
    union { uint32_t u; float f; } v; v.u = ((uint32_t)u) << 16;
    return v.f;
}

// ---------------------------------------------------------------------------
// fp32 -> bf16 bulk convert (n multiple of 4)
// ---------------------------------------------------------------------------
__global__ void f32_to_bf16_kernel(const float* __restrict__ in,
                                   ushort* __restrict__ out, long n) {
    long i = ((long)blockIdx.x * 256 + threadIdx.x) * 4;
    if (i >= n) return;
    float4 v = *(const float4*)(in + i);
    ushort4 o;
    o.x = f2bf(v.x); o.y = f2bf(v.y); o.z = f2bf(v.z); o.w = f2bf(v.w);
    *(ushort4*)(out + i) = o;
}

// ---------------------------------------------------------------------------
// All six weight transposes in one launch: W[K][N] fp32 -> Wt[N][K] bf16.
// grid = (256, 6). Output layout (shorts): Ws0t@0 Wn0t@65536 Ws1t@131072
// Wn1t@196608 Ws2t@262144 Wn2t@278528.
// ---------------------------------------------------------------------------
__global__ void transpose_w_all(const float* __restrict__ W0, const float* __restrict__ W1,
                                const float* __restrict__ W2, const float* __restrict__ W3,
                                const float* __restrict__ W4, const float* __restrict__ W5,
                                ushort* __restrict__ out) {
    const float* W; int Ndim; ushort* o;
    switch (blockIdx.y) {
        case 0: W = W0; Ndim = 256; o = out; break;
        case 1: W = W1; Ndim = 256; o = out + 65536; break;
        case 2: W = W2; Ndim = 256; o = out + 131072; break;
        case 3: W = W3; Ndim = 256; o = out + 196608; break;
        case 4: W = W4; Ndim = 64;  o = out + 262144; break;
        default: W = W5; Ndim = 64; o = out + 278528; break;
    }
    int id = blockIdx.x * 256 + threadIdx.x;  // id = n*256 + k
    int n = id >> 8;
    int k = id & 255;
    if (n >= Ndim) return;
    o[id] = f2bf(W[k * Ndim + n]);
}

// ---------------------------------------------------------------------------
// CSR build: histogram
// ---------------------------------------------------------------------------
__global__ void hist_kernel(const int* __restrict__ dst, int* __restrict__ cnt, int E) {
    int e = blockIdx.x * 256 + threadIdx.x;
    if (e < E) atomicAdd(&cnt[dst[e]], 1);
}

// ---------------------------------------------------------------------------
// 3-phase coalesced exclusive scan (n multiple of 4; n <= 64*1024)
// A: partial[b] = sum cnt[b*1024 .. +1024)
// ---------------------------------------------------------------------------
__global__ void scan_phase_a(const int* __restrict__ cnt, int* __restrict__ partial, int n) {
    __shared__ int red[4];
    int t = threadIdx.x;
    int i = blockIdx.x * 1024 + t * 4;
    int s = 0;
    if (i + 3 < n) {
        int4 v = *(const int4*)(cnt + i);
        s = v.x + v.y + v.z + v.w;
    }
#pragma unroll
    for (int d = 32; d; d >>= 1) s += __shfl_down(s, d, 64);
    if ((t & 63) == 0) red[t >> 6] = s;
    __syncthreads();
    if (t == 0) partial[blockIdx.x] = red[0] + red[1] + red[2] + red[3];
}

// B: exclusive scan of partial[0..nb), nb <= 64, single wave
__global__ void scan_phase_b(int* __restrict__ partial, int nb) {
    int t = threadIdx.x;  // 64 threads
    int own = (t < nb) ? partial[t] : 0;
    int v = own;
#pragma unroll
    for (int d = 1; d < 64; d <<= 1) {
        int u = __shfl_up(v, d, 64);
        if (t >= d) v += u;
    }
    if (t < nb) partial[t] = v - own;  // exclusive
}

// C: per-block scan + global base; writes off[] and cursor[]; off[n]=total
__global__ void scan_phase_c(const int* __restrict__ cnt, const int* __restrict__ partial,
                             int* __restrict__ off, int* __restrict__ cursor, int n) {
    __shared__ int tsum[256];
    int t = threadIdx.x;
    int i = blockIdx.x * 1024 + t * 4;
    int4 c = make_int4(0, 0, 0, 0);
    if (i + 3 < n) c = *(const int4*)(cnt + i);
    int s = c.x + c.y + c.z + c.w;
    tsum[t] = s;
    __syncthreads();
#pragma unroll
    for (int d = 1; d < 256; d <<= 1) {
        int u = (t >= d) ? tsum[t - d] : 0;
        __syncthreads();
        tsum[t] += u;
        __syncthreads();
    }
    int base = partial[blockIdx.x] + tsum[t] - s;  // exclusive prefix for elem i
    if (i + 3 < n) {
        int4 ov;
        ov.x = base;
        ov.y = ov.x + c.x;
        ov.z = ov.y + c.y;
        ov.w = ov.z + c.z;
        *(int4*)(off + i) = ov;
        *(int4*)(cursor + i) = ov;
        if (i + 4 == n) off[n] = ov.w + c.w;
    }
}

// ---------------------------------------------------------------------------
// CSR build: fill edge source-index lists
// ---------------------------------------------------------------------------
__global__ void fill_kernel(const int* __restrict__ src, const int* __restrict__ dst,
                            int* __restrict__ cursor, int* __restrict__ eidx, int E) {
    int e = blockIdx.x * 256 + threadIdx.x;
    if (e < E) {
        int p = atomicAdd(&cursor[dst[e]], 1);
        eidx[p] = src[e];
    }
}

// ---------------------------------------------------------------------------
// Gather-mean, bf16 in -> bf16 out. One wave per dst; lane owns 4 feats.
// 2-way unrolled edge loop for memory-level parallelism.
// ---------------------------------------------------------------------------
__global__ void gather_mean_bf16_kernel(const ushort* __restrict__ h,
                                        const int* __restrict__ off,
                                        const int* __restrict__ eidx,
                                        ushort* __restrict__ hn,
                                        int num_dst) {
    int w = blockIdx.x * 4 + (threadIdx.x >> 6);
    int lane = threadIdx.x & 63;
    if (w >= num_dst) return;
    int beg = off[w];
    int end = off[w + 1];
    float a0 = 0.f, a1 = 0.f, a2 = 0.f, a3 = 0.f;
    int i = beg;
    for (; i + 1 < end; i += 2) {
        int s0 = eidx[i];
        int s1 = eidx[i + 1];
        ushort4 v0 = ((const ushort4*)(h + (size_t)s0 * DH))[lane];
        ushort4 v1 = ((const ushort4*)(h + (size_t)s1 * DH))[lane];
        a0 += bf2f(v0.x) + bf2f(v1.x);
        a1 += bf2f(v0.y) + bf2f(v1.y);
        a2 += bf2f(v0.z) + bf2f(v1.z);
        a3 += bf2f(v0.w) + bf2f(v1.w);
    }
    if (i < end) {
        int s0 = eidx[i];
        ushort4 v0 = ((const ushort4*)(h + (size_t)s0 * DH))[lane];
        a0 += bf2f(v0.x); a1 += bf2f(v0.y); a2 += bf2f(v0.z); a3 += bf2f(v0.w);
    }
    float inv = 1.0f / fmaxf((float)(end - beg), 1.0f);
    ushort4 o;
    o.x = f2bf(a0 * inv); o.y = f2bf(a1 * inv);
    o.z = f2bf(a2 * inv); o.w = f2bf(a3 * inv);
    *(ushort4*)(hn + (size_t)w * DH + lane * 4) = o;
}

// ---------------------------------------------------------------------------
// MFMA dual GEMM: C[M,N] = Ad@Ws + An@Wn + bias (K=256). A: M x K bf16
// row-major. Wt: N x K bf16 (pre-transposed). Block: 128x64 tile, 4 waves,
// each wave 32x64 via 2x4 grid of 16x16x32 MFMAs.
// ---------------------------------------------------------------------------
template <bool RELU, bool OUT_BF16>
__global__ void gemm_mfma(const ushort* __restrict__ Ad,
                          const ushort* __restrict__ An,
                          const ushort* __restrict__ Wst,
                          const ushort* __restrict__ Wnt,
                          const float* __restrict__ bias,
                          void* __restrict__ Cv,
                          int M, int N) {
    const int K = 256;
    const int LDK = 40;  // padded k-stride (shorts): 80B rows, 16B-aligned
    __shared__ ushort As[128 * LDK];
    __shared__ ushort Bs[64 * LDK];

    int tid  = threadIdx.x;
    int lane = tid & 63;
    int wid  = tid >> 6;
    int quad = lane >> 4;
    int mr   = lane & 15;
    int row0 = blockIdx.y * 128;
    int col0 = blockIdx.x * 64;

    f32x4 acc[2][4];
#pragma unroll
    for (int i = 0; i < 2; ++i)
#pragma unroll
        for (int j = 0; j < 4; ++j) acc[i][j] = (f32x4){0.f, 0.f, 0.f, 0.f};

    for (int pass = 0; pass < 2; ++pass) {
        const ushort* A  = pass ? An : Ad;
        const ushort* Wt = pass ? Wnt : Wst;
        for (int k0 = 0; k0 < K; k0 += 32) {
#pragma unroll
            for (int c = 0; c < 2; ++c) {
                int chunk = tid + c * 256;
                int r   = chunk >> 2;
                int seg = chunk & 3;
                int row = row0 + r;
                uint4 v = make_uint4(0u, 0u, 0u, 0u);
                if (row < M) v = *(const uint4*)(A + (size_t)row * K + k0 + seg * 8);
                *(uint4*)(&As[r * LDK + seg * 8]) = v;
            }
            {
                int n   = tid >> 2;
                int seg = tid & 3;
                uint4 v = *(const uint4*)(Wt + (size_t)(col0 + n) * K + k0 + seg * 8);
                *(uint4*)(&Bs[n * LDK + seg * 8]) = v;
            }
            __syncthreads();
            short8 a[2], b[4];
#pragma unroll
            for (int mt = 0; mt < 2; ++mt)
                a[mt] = *(const short8*)(&As[(wid * 32 + mt * 16 + mr) * LDK + quad * 8]);
#pragma unroll
            for (int nt = 0; nt < 4; ++nt)
                b[nt] = *(const short8*)(&Bs[(nt * 16 + mr) * LDK + quad * 8]);
#pragma unroll
            for (int mt = 0; mt < 2; ++mt)
#pragma unroll
                for (int nt = 0; nt < 4; ++nt)
                    acc[mt][nt] = __builtin_amdgcn_mfma_f32_16x16x32_bf16(
                        a[mt], b[nt], acc[mt][nt], 0, 0, 0);
            __syncthreads();
        }
    }

    // Epilogue: C/D layout col = lane&15, row = quad*4 + reg
#pragma unroll
    for (int mt = 0; mt < 2; ++mt) {
#pragma unroll
        for (int i = 0; i < 4; ++i) {
            int row = row0 + wid * 32 + mt * 16 + quad * 4 + i;
            if (row >= M) continue;
#pragma unroll
            for (int nt = 0; nt < 4; ++nt) {
                int col = col0 + nt * 16 + mr;
                float v = acc[mt][nt][i] + bias[col];
                if (RELU) v = fmaxf(v, 0.0f);
                if (OUT_BF16) ((ushort*)Cv)[(size_t)row * N + col] = f2bf(v);
                else          ((float*)Cv)[(size_t)row * N + col] = v;
            }
        }
    }
}

// Helper: one layer's CSR build (cnt -> off/cursor -> eidx)
static void build_csr(const int* src, const int* dst, int E, int num_dst,
                      int* cnt, int* off, int* cursor, int* eidx, int* partial,
                      hipStream_t stream) {
    int nb = (num_dst + 1023) / 1024;
    hipMemsetAsync(cnt, 0, num_dst * sizeof(int), stream);
    hist_kernel<<<(E + 255) / 256, 256, 0, stream>>>(dst, cnt, E);
    scan_phase_a<<<nb, 256, 0, stream>>>(cnt, partial, num_dst);
    scan_phase_b<<<1, 64, 0, stream>>>(partial, nb);
    scan_phase_c<<<nb, 256, 0, stream>>>(cnt, partial, off, cursor, num_dst);
    fill_kernel<<<(E + 255) / 256, 256, 0, stream>>>(src, dst, cursor, eidx, E);
}

extern "C" void kernel_launch(void* const* d_in, const int* in_sizes, int n_in,
                              void* d_out, int out_size, void* d_ws, size_t ws_size,
                              hipStream_t stream) {
    const float* x    = (const float*)d_in[0];
    const int* src0   = (const int*)d_in[1];
    const int* dst0   = (const int*)d_in[2];
    const int* src1   = (const int*)d_in[3];
    const int* dst1   = (const int*)d_in[4];
    const int* src2   = (const int*)d_in[5];
    const int* dst2   = (const int*)d_in[6];
    const float* Ws0  = (const float*)d_in[10];
    const float* Wn0  = (const float*)d_in[11];
    const float* b0   = (const float*)d_in[12];
    const float* Ws1  = (const float*)d_in[13];
    const float* Wn1  = (const float*)d_in[14];
    const float* b1   = (const float*)d_in[15];
    const float* Ws2  = (const float*)d_in[16];
    const float* Wn2  = (const float*)d_in[17];
    const float* b2   = (const float*)d_in[18];
    float* out = (float*)d_out;

    int E0 = in_sizes[1];
    int E1 = in_sizes[3];
    int E2 = in_sizes[5];

    // Workspace layout (shorts first, then ints; all 16B aligned)
    ushort* wsu  = (ushort*)d_ws;
    ushort* xb   = wsu;                               // N0*256 (all of x, bf16)
    ushort* hn0b = xb   + (size_t)N0_SRC * DH;        // N1*256
    ushort* h1b  = hn0b + (size_t)N1_DST * DH;        // N1*256
    ushort* hn1b = h1b  + (size_t)N1_DST * DH;        // N2*256
    ushort* h2b  = hn1b + (size_t)N2_DST * DH;        // N2*256
    ushort* hn2b = h2b  + (size_t)N2_DST * DH;        // N3*256
    ushort* Wt   = hn2b + (size_t)N3_DST * DH;        // 294912 shorts (6 weights)
    ushort* Ws0t = Wt;
    ushort* Wn0t = Wt + 65536;
    ushort* Ws1t = Wt + 131072;
    ushort* Wn1t = Wt + 196608;
    ushort* Ws2t = Wt + 262144;
    ushort* Wn2t = Wt + 278528;
    int* cnt     = (int*)(Wt + 294912);               // max N1
    int* off     = cnt + N1_DST;                      // max N1+1 (+pad)
    int* cursor  = off + N1_DST + 4;                  // max N1
    int* eidx    = cursor + N1_DST;                   // max E0
    int* partial = eidx + 500000;                     // max 64 block partials

    // --- One-time per call: convert ALL of x and all weights to bf16 ---
    long nxb = (long)N0_SRC * DH;
    f32_to_bf16_kernel<<<(int)((nxb / 4 + 255) / 256), 256, 0, stream>>>(x, xb, nxb);
    transpose_w_all<<<dim3(256, 6), 256, 0, stream>>>(Ws0, Wn0, Ws1, Wn1, Ws2, Wn2, Wt);

    // ---- Layer 0: x -> h1 ----
    build_csr(src0, dst0, E0, N1_DST, cnt, off, cursor, eidx, partial, stream);
    gather_mean_bf16_kernel<<<(N1_DST + 3) / 4, 256, 0, stream>>>(xb, off, eidx, hn0b, N1_DST);
    {
        dim3 g(DH / 64, (N1_DST + 127) / 128);
        gemm_mfma<false, true><<<g, 256, 0, stream>>>(xb, hn0b, Ws0t, Wn0t, b0, h1b, N1_DST, DH);
    }

    // ---- Layer 1: h1 -> h2 (ReLU on output) ----
    build_csr(src1, dst1, E1, N2_DST, cnt, off, cursor, eidx, partial, stream);
    gather_mean_bf16_kernel<<<(N2_DST + 3) / 4, 256, 0, stream>>>(h1b, off, eidx, hn1b, N2_DST);
    {
        dim3 g(DH / 64, (N2_DST + 127) / 128);
        gemm_mfma<true, true><<<g, 256, 0, stream>>>(h1b, hn1b, Ws1t, Wn1t, b1, h2b, N2_DST, DH);
    }

    // ---- Layer 2: h2 -> out (fp32 output) ----
    build_csr(src2, dst2, E2, N3_DST, cnt, off, cursor, eidx, partial, stream);
    gather_mean_bf16_kernel<<<(N3_DST + 3) / 4, 256, 0, stream>>>(h2b, off, eidx, hn2b, N3_DST);
    {
        dim3 g(DOUT / 64, (N3_DST + 127) / 128);
        gemm_mfma<false, false><<<g, 256, 0, stream>>>(h2b, hn2b, Ws2t, Wn2t, b2, out, N3_DST, DOUT);
    }
}

// Round 5
// 523.527 us; speedup vs baseline: 5.3082x; 1.0899x over previous
//
#include <hip/hip_runtime.h>

// Problem constants (from reference file)
#define N0_SRC 200000
#define N1_DST 50000
#define N2_DST 12000
#define N3_DST 3000
#define NTOT_DST 65000   // N1+N2+N3 (multiple of 4; scan uses 64 blocks)
#define DH 256           // D_IN == D_H == 256
#define DOUT 64
#define EMAX_TOT 650000  // E0+E1+E2

typedef __attribute__((ext_vector_type(8))) short short8;
typedef __attribute__((ext_vector_type(4))) float f32x4;

__device__ __forceinline__ ushort f2bf(float f) {
    union { float f; uint32_t u; } v; v.f = f;
    uint32_t r = (v.u + 0x7FFF + ((v.u >> 16) & 1)) >> 16;  // RNE
    return (ushort)r;
}
__device__ __forceinline__ float bf2f(ushort u) {
    union { uint32_t u; float f; } v; v.u = ((uint32_t)u) << 16;
    return v.f;
}

// ---------------------------------------------------------------------------
// fp32 -> bf16 bulk convert (n multiple of 4)
// ---------------------------------------------------------------------------
__global__ void f32_to_bf16_kernel(const float* __restrict__ in,
                                   ushort* __restrict__ out, long n) {
    long i = ((long)blockIdx.x * 256 + threadIdx.x) * 4;
    if (i >= n) return;
    float4 v = *(const float4*)(in + i);
    ushort4 o;
    o.x = f2bf(v.x); o.y = f2bf(v.y); o.z = f2bf(v.z); o.w = f2bf(v.w);
    *(ushort4*)(out + i) = o;
}

// ---------------------------------------------------------------------------
// All six weight transposes in one launch: W[K][N] fp32 -> Wt[N][K] bf16.
// grid = (256, 6).
// ---------------------------------------------------------------------------
__global__ void transpose_w_all(const float* __restrict__ W0, const float* __restrict__ W1,
                                const float* __restrict__ W2, const float* __restrict__ W3,
                                const float* __restrict__ W4, const float* __restrict__ W5,
                                ushort* __restrict__ out) {
    const float* W; int Ndim; ushort* o;
    switch (blockIdx.y) {
        case 0: W = W0; Ndim = 256; o = out; break;
        case 1: W = W1; Ndim = 256; o = out + 65536; break;
        case 2: W = W2; Ndim = 256; o = out + 131072; break;
        case 3: W = W3; Ndim = 256; o = out + 196608; break;
        case 4: W = W4; Ndim = 64;  o = out + 262144; break;
        default: W = W5; Ndim = 64; o = out + 278528; break;
    }
    int id = blockIdx.x * 256 + threadIdx.x;  // id = n*256 + k
    int n = id >> 8;
    int k = id & 255;
    if (n >= Ndim) return;
    o[id] = f2bf(W[k * Ndim + n]);
}

// ---------------------------------------------------------------------------
// Batched CSR build over all 3 layers (cnt/cursor concatenated; eidx global)
// ---------------------------------------------------------------------------
__global__ void hist3_kernel(const int* __restrict__ d0, int E0,
                             const int* __restrict__ d1, int E1,
                             const int* __restrict__ d2, int E2,
                             int* __restrict__ cnt) {
    int layer = blockIdx.y;
    const int* dst; int E; int base;
    if (layer == 0)      { dst = d0; E = E0; base = 0; }
    else if (layer == 1) { dst = d1; E = E1; base = N1_DST; }
    else                 { dst = d2; E = E2; base = N1_DST + N2_DST; }
    int e = blockIdx.x * 256 + threadIdx.x;
    if (e < E) atomicAdd(&cnt[base + dst[e]], 1);
}

__global__ void fill3_kernel(const int* __restrict__ s0, const int* __restrict__ d0, int E0,
                             const int* __restrict__ s1, const int* __restrict__ d1, int E1,
                             const int* __restrict__ s2, const int* __restrict__ d2, int E2,
                             int* __restrict__ cursor, int* __restrict__ eidx) {
    int layer = blockIdx.y;
    const int* src; const int* dst; int E; int base;
    if (layer == 0)      { src = s0; dst = d0; E = E0; base = 0; }
    else if (layer == 1) { src = s1; dst = d1; E = E1; base = N1_DST; }
    else                 { src = s2; dst = d2; E = E2; base = N1_DST + N2_DST; }
    int e = blockIdx.x * 256 + threadIdx.x;
    if (e < E) {
        int p = atomicAdd(&cursor[base + dst[e]], 1);
        eidx[p] = src[e];
    }
}

// ---------------------------------------------------------------------------
// 3-phase coalesced exclusive scan (n multiple of 4; n <= 64*1024)
// ---------------------------------------------------------------------------
__global__ void scan_phase_a(const int* __restrict__ cnt, int* __restrict__ partial, int n) {
    __shared__ int red[4];
    int t = threadIdx.x;
    int i = blockIdx.x * 1024 + t * 4;
    int s = 0;
    if (i + 3 < n) {
        int4 v = *(const int4*)(cnt + i);
        s = v.x + v.y + v.z + v.w;
    }
#pragma unroll
    for (int d = 32; d; d >>= 1) s += __shfl_down(s, d, 64);
    if ((t & 63) == 0) red[t >> 6] = s;
    __syncthreads();
    if (t == 0) partial[blockIdx.x] = red[0] + red[1] + red[2] + red[3];
}

__global__ void scan_phase_b(int* __restrict__ partial, int nb) {
    int t = threadIdx.x;  // 64 threads
    int own = (t < nb) ? partial[t] : 0;
    int v = own;
#pragma unroll
    for (int d = 1; d < 64; d <<= 1) {
        int u = __shfl_up(v, d, 64);
        if (t >= d) v += u;
    }
    if (t < nb) partial[t] = v - own;  // exclusive
}

__global__ void scan_phase_c(const int* __restrict__ cnt, const int* __restrict__ partial,
                             int* __restrict__ off, int* __restrict__ cursor, int n) {
    __shared__ int tsum[256];
    int t = threadIdx.x;
    int i = blockIdx.x * 1024 + t * 4;
    int4 c = make_int4(0, 0, 0, 0);
    if (i + 3 < n) c = *(const int4*)(cnt + i);
    int s = c.x + c.y + c.z + c.w;
    tsum[t] = s;
    __syncthreads();
#pragma unroll
    for (int d = 1; d < 256; d <<= 1) {
        int u = (t >= d) ? tsum[t - d] : 0;
        __syncthreads();
        tsum[t] += u;
        __syncthreads();
    }
    int base = partial[blockIdx.x] + tsum[t] - s;
    if (i + 3 < n) {
        int4 ov;
        ov.x = base;
        ov.y = ov.x + c.x;
        ov.z = ov.y + c.y;
        ov.w = ov.z + c.z;
        *(int4*)(off + i) = ov;
        *(int4*)(cursor + i) = ov;
        if (i + 4 == n) off[n] = ov.w + c.w;
    }
}

// ---------------------------------------------------------------------------
// Gather-mean, bf16 in -> bf16 out. One wave per dst; lane owns 4 feats.
// 4-way unrolled edge loop for memory-level parallelism.
// ---------------------------------------------------------------------------
__global__ void gather_mean_bf16_kernel(const ushort* __restrict__ h,
                                        const int* __restrict__ off,
                                        const int* __restrict__ eidx,
                                        ushort* __restrict__ hn,
                                        int num_dst) {
    int w = blockIdx.x * 4 + (threadIdx.x >> 6);
    int lane = threadIdx.x & 63;
    if (w >= num_dst) return;
    int beg = off[w];
    int end = off[w + 1];
    float a0 = 0.f, a1 = 0.f, a2 = 0.f, a3 = 0.f;
    int i = beg;
    for (; i + 3 < end; i += 4) {
        int s0 = eidx[i], s1 = eidx[i + 1], s2 = eidx[i + 2], s3 = eidx[i + 3];
        ushort4 v0 = ((const ushort4*)(h + (size_t)s0 * DH))[lane];
        ushort4 v1 = ((const ushort4*)(h + (size_t)s1 * DH))[lane];
        ushort4 v2 = ((const ushort4*)(h + (size_t)s2 * DH))[lane];
        ushort4 v3 = ((const ushort4*)(h + (size_t)s3 * DH))[lane];
        a0 += (bf2f(v0.x) + bf2f(v1.x)) + (bf2f(v2.x) + bf2f(v3.x));
        a1 += (bf2f(v0.y) + bf2f(v1.y)) + (bf2f(v2.y) + bf2f(v3.y));
        a2 += (bf2f(v0.z) + bf2f(v1.z)) + (bf2f(v2.z) + bf2f(v3.z));
        a3 += (bf2f(v0.w) + bf2f(v1.w)) + (bf2f(v2.w) + bf2f(v3.w));
    }
    for (; i < end; ++i) {
        int s0 = eidx[i];
        ushort4 v0 = ((const ushort4*)(h + (size_t)s0 * DH))[lane];
        a0 += bf2f(v0.x); a1 += bf2f(v0.y); a2 += bf2f(v0.z); a3 += bf2f(v0.w);
    }
    float inv = 1.0f / fmaxf((float)(end - beg), 1.0f);
    ushort4 o;
    o.x = f2bf(a0 * inv); o.y = f2bf(a1 * inv);
    o.z = f2bf(a2 * inv); o.w = f2bf(a3 * inv);
    *(ushort4*)(hn + (size_t)w * DH + lane * 4) = o;
}

// ---------------------------------------------------------------------------
// MFMA dual GEMM: C[M,N] = Ad@Ws + An@Wn + bias (K=256). A: M x K bf16
// row-major. Wt: N x K bf16 (pre-transposed). Block: 128 x BN tile, 4 waves,
// each wave 32 x BN via 2 x (BN/16) grid of 16x16x32 MFMAs.
// ---------------------------------------------------------------------------
template <int BN, bool RELU, bool OUT_BF16>
__global__ void gemm_mfma(const ushort* __restrict__ Ad,
                          const ushort* __restrict__ An,
                          const ushort* __restrict__ Wst,
                          const ushort* __restrict__ Wnt,
                          const float* __restrict__ bias,
                          void* __restrict__ Cv,
                          int M, int N) {
    const int K = 256;
    const int LDK = 40;  // padded k-stride (shorts): 80B rows, 16B-aligned
    const int NT = BN / 16;
    __shared__ ushort As[128 * LDK];
    __shared__ ushort Bs[BN * LDK];

    int tid  = threadIdx.x;
    int lane = tid & 63;
    int wid  = tid >> 6;
    int quad = lane >> 4;
    int mr   = lane & 15;
    int row0 = blockIdx.y * 128;
    int col0 = blockIdx.x * BN;

    f32x4 acc[2][NT];
#pragma unroll
    for (int i = 0; i < 2; ++i)
#pragma unroll
        for (int j = 0; j < NT; ++j) acc[i][j] = (f32x4){0.f, 0.f, 0.f, 0.f};

    for (int pass = 0; pass < 2; ++pass) {
        const ushort* A  = pass ? An : Ad;
        const ushort* Wt = pass ? Wnt : Wst;
        for (int k0 = 0; k0 < K; k0 += 32) {
            // Stage A tile: 128 rows x 32 k = 512 chunks of 8 bf16; 2/thread
#pragma unroll
            for (int c = 0; c < 2; ++c) {
                int chunk = tid + c * 256;
                int r   = chunk >> 2;
                int seg = chunk & 3;
                int row = row0 + r;
                uint4 v = make_uint4(0u, 0u, 0u, 0u);
                if (row < M) v = *(const uint4*)(A + (size_t)row * K + k0 + seg * 8);
                *(uint4*)(&As[r * LDK + seg * 8]) = v;
            }
            // Stage B tile: BN n-rows x 32 k; BN/64 chunks per thread
#pragma unroll
            for (int c = 0; c < BN / 64; ++c) {
                int chunk = tid + c * 256;
                int n   = chunk >> 2;
                int seg = chunk & 3;
                uint4 v = *(const uint4*)(Wt + (size_t)(col0 + n) * K + k0 + seg * 8);
                *(uint4*)(&Bs[n * LDK + seg * 8]) = v;
            }
            __syncthreads();
            short8 a[2], b[NT];
#pragma unroll
            for (int mt = 0; mt < 2; ++mt)
                a[mt] = *(const short8*)(&As[(wid * 32 + mt * 16 + mr) * LDK + quad * 8]);
#pragma unroll
            for (int nt = 0; nt < NT; ++nt)
                b[nt] = *(const short8*)(&Bs[(nt * 16 + mr) * LDK + quad * 8]);
#pragma unroll
            for (int mt = 0; mt < 2; ++mt)
#pragma unroll
                for (int nt = 0; nt < NT; ++nt)
                    acc[mt][nt] = __builtin_amdgcn_mfma_f32_16x16x32_bf16(
                        a[mt], b[nt], acc[mt][nt], 0, 0, 0);
            __syncthreads();
        }
    }

    // Epilogue: C/D layout col = lane&15, row = quad*4 + reg
#pragma unroll
    for (int mt = 0; mt < 2; ++mt) {
#pragma unroll
        for (int i = 0; i < 4; ++i) {
            int row = row0 + wid * 32 + mt * 16 + quad * 4 + i;
            if (row >= M) continue;
#pragma unroll
            for (int nt = 0; nt < NT; ++nt) {
                int col = col0 + nt * 16 + mr;
                float v = acc[mt][nt][i] + bias[col];
                if (RELU) v = fmaxf(v, 0.0f);
                if (OUT_BF16) ((ushort*)Cv)[(size_t)row * N + col] = f2bf(v);
                else          ((float*)Cv)[(size_t)row * N + col] = v;
            }
        }
    }
}

extern "C" void kernel_launch(void* const* d_in, const int* in_sizes, int n_in,
                              void* d_out, int out_size, void* d_ws, size_t ws_size,
                              hipStream_t stream) {
    const float* x    = (const float*)d_in[0];
    const int* src0   = (const int*)d_in[1];
    const int* dst0   = (const int*)d_in[2];
    const int* src1   = (const int*)d_in[3];
    const int* dst1   = (const int*)d_in[4];
    const int* src2   = (const int*)d_in[5];
    const int* dst2   = (const int*)d_in[6];
    const float* Ws0  = (const float*)d_in[10];
    const float* Wn0  = (const float*)d_in[11];
    const float* b0   = (const float*)d_in[12];
    const float* Ws1  = (const float*)d_in[13];
    const float* Wn1  = (const float*)d_in[14];
    const float* b1   = (const float*)d_in[15];
    const float* Ws2  = (const float*)d_in[16];
    const float* Wn2  = (const float*)d_in[17];
    const float* b2   = (const float*)d_in[18];
    float* out = (float*)d_out;

    int E0 = in_sizes[1];
    int E1 = in_sizes[3];
    int E2 = in_sizes[5];

    // Workspace layout (shorts first, then ints; all 16B aligned)
    ushort* wsu  = (ushort*)d_ws;
    ushort* xb   = wsu;                               // N0*256 (all of x, bf16)
    ushort* hn0b = xb   + (size_t)N0_SRC * DH;        // N1*256
    ushort* h1b  = hn0b + (size_t)N1_DST * DH;        // N1*256
    ushort* hn1b = h1b  + (size_t)N1_DST * DH;        // N2*256
    ushort* h2b  = hn1b + (size_t)N2_DST * DH;        // N2*256
    ushort* hn2b = h2b  + (size_t)N2_DST * DH;        // N3*256
    ushort* Wt   = hn2b + (size_t)N3_DST * DH;        // 294912 shorts (6 weights)
    ushort* Ws0t = Wt;
    ushort* Wn0t = Wt + 65536;
    ushort* Ws1t = Wt + 131072;
    ushort* Wn1t = Wt + 196608;
    ushort* Ws2t = Wt + 262144;
    ushort* Wn2t = Wt + 278528;
    int* cnt     = (int*)(Wt + 294912);               // NTOT_DST
    int* off     = cnt + NTOT_DST;                    // NTOT_DST+1 (+pad)
    int* cursor  = off + NTOT_DST + 4;                // NTOT_DST
    int* eidx    = cursor + NTOT_DST;                 // EMAX_TOT
    int* partial = eidx + EMAX_TOT;                   // 64 block partials

    // --- One-time per call: convert ALL of x and all weights to bf16 ---
    long nxb = (long)N0_SRC * DH;
    f32_to_bf16_kernel<<<(int)((nxb / 4 + 255) / 256), 256, 0, stream>>>(x, xb, nxb);
    transpose_w_all<<<dim3(256, 6), 256, 0, stream>>>(Ws0, Wn0, Ws1, Wn1, Ws2, Wn2, Wt);

    // --- Batched CSR build for all 3 layers ---
    int Emax = max(max(E0, E1), E2);
    int nb = (NTOT_DST + 1023) / 1024;  // = 64
    hipMemsetAsync(cnt, 0, NTOT_DST * sizeof(int), stream);
    hist3_kernel<<<dim3((Emax + 255) / 256, 3), 256, 0, stream>>>(dst0, E0, dst1, E1, dst2, E2, cnt);
    scan_phase_a<<<nb, 256, 0, stream>>>(cnt, partial, NTOT_DST);
    scan_phase_b<<<1, 64, 0, stream>>>(partial, nb);
    scan_phase_c<<<nb, 256, 0, stream>>>(cnt, partial, off, cursor, NTOT_DST);
    fill3_kernel<<<dim3((Emax + 255) / 256, 3), 256, 0, stream>>>(
        src0, dst0, E0, src1, dst1, E1, src2, dst2, E2, cursor, eidx);

    const int* off0 = off;
    const int* off1 = off + N1_DST;
    const int* off2 = off + N1_DST + N2_DST;

    // ---- Layer 0: x -> h1 ----
    gather_mean_bf16_kernel<<<(N1_DST + 3) / 4, 256, 0, stream>>>(xb, off0, eidx, hn0b, N1_DST);
    {
        dim3 g(DH / 128, (N1_DST + 127) / 128);
        gemm_mfma<128, false, true><<<g, 256, 0, stream>>>(xb, hn0b, Ws0t, Wn0t, b0, h1b, N1_DST, DH);
    }

    // ---- Layer 1: h1 -> h2 (ReLU on output) ----
    gather_mean_bf16_kernel<<<(N2_DST + 3) / 4, 256, 0, stream>>>(h1b, off1, eidx, hn1b, N2_DST);
    {
        dim3 g(DH / 128, (N2_DST + 127) / 128);
        gemm_mfma<128, true, true><<<g, 256, 0, stream>>>(h1b, hn1b, Ws1t, Wn1t, b1, h2b, N2_DST, DH);
    }

    // ---- Layer 2: h2 -> out (fp32 output) ----
    gather_mean_bf16_kernel<<<(N3_DST + 3) / 4, 256, 0, stream>>>(h2b, off2, eidx, hn2b, N3_DST);
    {
        dim3 g(DOUT / 64, (N3_DST + 127) / 128);
        gemm_mfma<64, false, false><<<g, 256, 0, stream>>>(h2b, hn2b, Ws2t, Wn2t, b2, out, N3_DST, DOUT);
    }
}